// Round 1
// baseline (387.095 us; speedup 1.0000x reference)
//
#include <hip/hip_runtime.h>
#include <math.h>

#define BATCH 1024
#define SEQ   200
#define DIN   128
#define DOUT  128

// ================= K1: low_new = low_capsule @ S =================
// A [204800 x 128] * S [128 x 128] -> out [204800 x 128], fp32.
// 64 rows x 128 cols per block, 256 threads, thread tile 4 rows x 8 cols.
__global__ __launch_bounds__(256) void k_gemm(const float* __restrict__ A,
                                              const float* __restrict__ S,
                                              float* __restrict__ out) {
    __shared__ float sA[64 * 132];   // +4 pad so column (k-vector) reads spread banks
    __shared__ float sS[32 * 128];   // S staged in 4 chunks of 32 k-rows
    const int t = threadIdx.x;
    const long row0 = (long)blockIdx.x * 64;

    // stage A tile (coalesced float4)
    {
        const int c4 = t & 31;
        const int r0 = t >> 5;
        for (int r = r0; r < 64; r += 8) {
            float4 v = *(const float4*)&A[(row0 + r) * DIN + 4 * c4];
            *(float4*)&sA[r * 132 + 4 * c4] = v;
        }
    }

    const int rg = t & 15;   // rows rg + 16j, j=0..3
    const int cg = t >> 4;   // cols 8cg .. 8cg+7
    float4 acc[4][2];
#pragma unroll
    for (int j = 0; j < 4; ++j) {
        acc[j][0] = make_float4(0.f, 0.f, 0.f, 0.f);
        acc[j][1] = make_float4(0.f, 0.f, 0.f, 0.f);
    }

    for (int kc = 0; kc < 4; ++kc) {
        __syncthreads();   // previous sS chunk fully consumed
        {
            const int c4 = t & 31;
            const int r0 = t >> 5;
            for (int r = r0; r < 32; r += 8) {
                float4 v = *(const float4*)&S[(32 * kc + r) * DOUT + 4 * c4];
                *(float4*)&sS[r * 128 + 4 * c4] = v;
            }
        }
        __syncthreads();
#pragma unroll
        for (int k4 = 0; k4 < 8; ++k4) {
            float4 a[4];
#pragma unroll
            for (int j = 0; j < 4; ++j)
                a[j] = *(const float4*)&sA[(rg + 16 * j) * 132 + 32 * kc + 4 * k4];
#pragma unroll
            for (int kk = 0; kk < 4; ++kk) {
                float4 s0 = *(const float4*)&sS[(4 * k4 + kk) * 128 + 8 * cg];
                float4 s1 = *(const float4*)&sS[(4 * k4 + kk) * 128 + 8 * cg + 4];
#pragma unroll
                for (int j = 0; j < 4; ++j) {
                    float aj = (kk == 0) ? a[j].x : (kk == 1) ? a[j].y
                             : (kk == 2) ? a[j].z : a[j].w;
                    acc[j][0].x += aj * s0.x; acc[j][0].y += aj * s0.y;
                    acc[j][0].z += aj * s0.z; acc[j][0].w += aj * s0.w;
                    acc[j][1].x += aj * s1.x; acc[j][1].y += aj * s1.y;
                    acc[j][1].z += aj * s1.z; acc[j][1].w += aj * s1.w;
                }
            }
        }
    }
#pragma unroll
    for (int j = 0; j < 4; ++j) {
        *(float4*)&out[(row0 + rg + 16 * j) * DOUT + 8 * cg]     = acc[j][0];
        *(float4*)&out[(row0 + rg + 16 * j) * DOUT + 8 * cg + 4] = acc[j][1];
    }
}

// ================= K2: one routing iteration =================
// Block = one batch element b, 256 threads.
// iter 0: logits = Bm             ; delta -> atomicAdd acc0
// iter 1: logits = Bm+acc0        ; delta -> atomicAdd acc1
// iter 2: logits = Bm+acc0+acc1   ; write high to out, no delta
__global__ __launch_bounds__(256) void k_routing_iter(
    const float* __restrict__ low,    // [B][200][128]
    const float* __restrict__ Bm,     // [3][200]
    const int*   __restrict__ seq,    // [B]
    float* __restrict__ acc0,         // [600]
    float* __restrict__ acc1,         // [600]
    float* __restrict__ out,          // [B][3][128]
    int iter) {
    __shared__ float sW[3][200];
    __shared__ float sHigh[3][128];
    __shared__ float sPart[8][3][128];
    __shared__ float sDelta[600];

    const int b = blockIdx.x;
    const int t = threadIdx.x;
    const int lane = t & 63;
    const int w = t >> 6;
    const int n = seq[b];
    const float* lowb = low + (size_t)b * (SEQ * DIN);

    // ---- Pass A: masked softmax, wave w handles k=w ----
    if (w < 3) {
        const int k = w;
        float m = -INFINITY;
        for (int l = lane; l < SEQ; l += 64) {
            float v = Bm[k * SEQ + l];
            if (iter >= 1) v += acc0[k * SEQ + l];
            if (iter >= 2) v += acc1[k * SEQ + l];
            if (l < n) m = fmaxf(m, v);
        }
        for (int off = 32; off; off >>= 1) m = fmaxf(m, __shfl_xor(m, off, 64));
        float s = 0.f;
        for (int l = lane; l < SEQ; l += 64) {
            float v = Bm[k * SEQ + l];
            if (iter >= 1) v += acc0[k * SEQ + l];
            if (iter >= 2) v += acc1[k * SEQ + l];
            float p = (l < n) ? expf(v - m) : 0.f;
            sW[k][l] = p;
            s += p;
        }
        for (int off = 32; off; off >>= 1) s += __shfl_xor(s, off, 64);
        float rs = 1.f / s;
        for (int l = lane; l < SEQ; l += 64) sW[k][l] *= rs;
    }
    __syncthreads();

    // ---- Pass B: high_pre partials (thread = 4-wide e chunk x l-part) ----
    {
        const int e4 = t & 31;
        const int part = t >> 5;
        float4 h0 = make_float4(0.f, 0.f, 0.f, 0.f);
        float4 h1 = h0, h2 = h0;
        for (int l = part; l < SEQ; l += 8) {
            float4 lv = *(const float4*)&lowb[l * DIN + 4 * e4];
            float w0 = sW[0][l], w1 = sW[1][l], w2 = sW[2][l];
            h0.x += w0 * lv.x; h0.y += w0 * lv.y; h0.z += w0 * lv.z; h0.w += w0 * lv.w;
            h1.x += w1 * lv.x; h1.y += w1 * lv.y; h1.z += w1 * lv.z; h1.w += w1 * lv.w;
            h2.x += w2 * lv.x; h2.y += w2 * lv.y; h2.z += w2 * lv.z; h2.w += w2 * lv.w;
        }
        *(float4*)&sPart[part][0][4 * e4] = h0;
        *(float4*)&sPart[part][1][4 * e4] = h1;
        *(float4*)&sPart[part][2][4 * e4] = h2;
    }
    __syncthreads();

    // ---- Reduce over parts + squash (sum of squares over k, per e) ----
    if (t < 128) {
        const int e = t;
        float h0 = 0.f, h1 = 0.f, h2 = 0.f;
#pragma unroll
        for (int p = 0; p < 8; ++p) {
            h0 += sPart[p][0][e];
            h1 += sPart[p][1][e];
            h2 += sPart[p][2][e];
        }
        float sq = h0 * h0 + h1 * h1 + h2 * h2;
        float scale = sq / (1.f + sq) / sqrtf(sq + 1e-9f);
        h0 *= scale; h1 *= scale; h2 *= scale;
        sHigh[0][e] = h0; sHigh[1][e] = h1; sHigh[2][e] = h2;
        if (iter == 2) {
            out[((size_t)b * 3 + 0) * DOUT + e] = h0;
            out[((size_t)b * 3 + 1) * DOUT + e] = h1;
            out[((size_t)b * 3 + 2) * DOUT + e] = h2;
        }
    }
    if (iter == 2) return;   // uniform exit, no barrier divergence
    __syncthreads();

    // ---- Pass C: delta[k][l] = sum_e high[k][e]*low[l][e] ----
    {
        const int el = lane & 31;   // e chunk 4*el..4*el+3
        const int sub = lane >> 5;  // which l of the pair
        float4 g0 = *(const float4*)&sHigh[0][4 * el];
        float4 g1 = *(const float4*)&sHigh[1][4 * el];
        float4 g2 = *(const float4*)&sHigh[2][4 * el];
#pragma unroll 5
        for (int i = 0; i < 25; ++i) {
            int l = 2 * (w * 25 + i) + sub;
            float4 lv = *(const float4*)&lowb[l * DIN + 4 * el];
            float c0 = g0.x * lv.x + g0.y * lv.y + g0.z * lv.z + g0.w * lv.w;
            float c1 = g1.x * lv.x + g1.y * lv.y + g1.z * lv.z + g1.w * lv.w;
            float c2 = g2.x * lv.x + g2.y * lv.y + g2.z * lv.z + g2.w * lv.w;
            for (int off = 16; off; off >>= 1) {
                c0 += __shfl_xor(c0, off, 32);
                c1 += __shfl_xor(c1, off, 32);
                c2 += __shfl_xor(c2, off, 32);
            }
            if (el == 0) {
                sDelta[0 * SEQ + l] = c0;
                sDelta[1 * SEQ + l] = c1;
                sDelta[2 * SEQ + l] = c2;
            }
        }
    }
    __syncthreads();
    float* accN = (iter == 0) ? acc0 : acc1;
    for (int idx = t; idx < 600; idx += 256) atomicAdd(&accN[idx], sDelta[idx]);
}

extern "C" void kernel_launch(void* const* d_in, const int* in_sizes, int n_in,
                              void* d_out, int out_size, void* d_ws, size_t ws_size,
                              hipStream_t stream) {
    const float* low_capsule = (const float*)d_in[0];   // [1024][200][128]
    const float* B_matrix    = (const float*)d_in[1];   // [1][3][200]
    const float* S_matrix    = (const float*)d_in[2];   // [128][128]
    const int*   seq_len     = (const int*)d_in[3];     // [1024]
    float* out = (float*)d_out;                         // [1024][3][128]

    float* low_new = (float*)d_ws;                       // 26,214,400 floats
    float* acc = low_new + (size_t)BATCH * SEQ * DOUT;   // acc0[600], acc1[600]

    hipMemsetAsync(acc, 0, 2 * 600 * sizeof(float), stream);

    k_gemm<<<(BATCH * SEQ) / 64, 256, 0, stream>>>(low_capsule, S_matrix, low_new);

    k_routing_iter<<<BATCH, 256, 0, stream>>>(low_new, B_matrix, seq_len,
                                              acc, acc + 600, out, 0);
    k_routing_iter<<<BATCH, 256, 0, stream>>>(low_new, B_matrix, seq_len,
                                              acc, acc + 600, out, 1);
    k_routing_iter<<<BATCH, 256, 0, stream>>>(low_new, B_matrix, seq_len,
                                              acc, acc + 600, out, 2);
}

// Round 2
// 332.225 us; speedup vs baseline: 1.1652x; 1.1652x over previous
//
#include <hip/hip_runtime.h>
#include <math.h>

#define BATCH 1024
#define SEQ   200
#define DIN   128
#define DOUT  128

typedef __attribute__((ext_vector_type(8))) short short8;
typedef __attribute__((ext_vector_type(4))) float f32x4;

// split fp32 -> bf16 hi (round-half-up) + bf16 lo (RTZ of exact residual)
// combined representation error ~2^-17 relative
__device__ __forceinline__ void split2(float f, short& h, short& l) {
    unsigned u = __float_as_uint(f);
    unsigned r = u + 0x8000u;
    h = (short)(r >> 16);
    float hf = __uint_as_float(r & 0xffff0000u);
    float res = f - hf;
    l = (short)(__float_as_uint(res) >> 16);
}

// ---- pre-split S into MFMA B-fragment order ----
// Sp[hi: idx, lo: 16384+idx], idx = ((nt*4+kt)*64+lane)*8 + j
// element: k = kt*32 + (lane>>4)*8 + j, n = nt*16 + (lane&15)
__global__ __launch_bounds__(256) void k_presplit(const float* __restrict__ S,
                                                  short* __restrict__ Sp) {
    int g = blockIdx.x * 256 + threadIdx.x;          // 0..16383
    int j = g & 7, lane = (g >> 3) & 63, kt = (g >> 9) & 3, nt = g >> 11;
    int k = kt * 32 + (lane >> 4) * 8 + j;
    int n = nt * 16 + (lane & 15);
    short h, l;
    split2(S[k * DOUT + n], h, l);
    Sp[g] = h;
    Sp[16384 + g] = l;
}

// ---- K1: low_new = A @ S via bf16-split MFMA (C = ah*sh + ah*sl + al*sh) ----
// block = 256 thr (4 waves), 64 rows; wave w owns cols [32w, 32w+32)
__global__ __launch_bounds__(256) void k_gemm(const float* __restrict__ A,
                                              const short* __restrict__ Sp,
                                              float* __restrict__ out) {
    const int t = threadIdx.x;
    const int w = t >> 6, lane = t & 63;
    const long row0 = (long)blockIdx.x * 64;

    short8 bfrag[2][2][4];   // [split][ntl][kt]
#pragma unroll
    for (int s = 0; s < 2; ++s)
#pragma unroll
        for (int ntl = 0; ntl < 2; ++ntl)
#pragma unroll
            for (int kt = 0; kt < 4; ++kt)
                bfrag[s][ntl][kt] = *(const short8*)(Sp + s * 16384 +
                    (((2 * w + ntl) * 4 + kt) * 64 + lane) * 8);

    f32x4 acc[4][2];
    const f32x4 zz = {0.f, 0.f, 0.f, 0.f};
#pragma unroll
    for (int mt = 0; mt < 4; ++mt) { acc[mt][0] = zz; acc[mt][1] = zz; }

#pragma unroll
    for (int kt = 0; kt < 4; ++kt) {
#pragma unroll
        for (int mt = 0; mt < 4; ++mt) {
            const float* ap = A + (row0 + mt * 16 + (lane & 15)) * DIN
                              + kt * 32 + (lane >> 4) * 8;
            float av[8];
            *(float4*)&av[0] = *(const float4*)ap;
            *(float4*)&av[4] = *(const float4*)(ap + 4);
            short8 ah, al;
#pragma unroll
            for (int j = 0; j < 8; ++j) {
                short h, l;
                split2(av[j], h, l);
                ah[j] = h; al[j] = l;
            }
#pragma unroll
            for (int ntl = 0; ntl < 2; ++ntl) {
                acc[mt][ntl] = __builtin_amdgcn_mfma_f32_16x16x32_bf16(
                    ah, bfrag[0][ntl][kt], acc[mt][ntl], 0, 0, 0);
                acc[mt][ntl] = __builtin_amdgcn_mfma_f32_16x16x32_bf16(
                    al, bfrag[0][ntl][kt], acc[mt][ntl], 0, 0, 0);
                acc[mt][ntl] = __builtin_amdgcn_mfma_f32_16x16x32_bf16(
                    ah, bfrag[1][ntl][kt], acc[mt][ntl], 0, 0, 0);
            }
        }
    }
    // C/D layout: col = lane&15, row = (lane>>4)*4 + r
    const int cq = lane >> 4, cn = lane & 15;
#pragma unroll
    for (int mt = 0; mt < 4; ++mt)
#pragma unroll
        for (int ntl = 0; ntl < 2; ++ntl) {
            long r0 = row0 + mt * 16 + cq * 4;
            int col = w * 32 + ntl * 16 + cn;
#pragma unroll
            for (int r = 0; r < 4; ++r)
                out[(r0 + r) * DOUT + col] = acc[mt][ntl][r];
        }
}

// ---- K2: one routing iteration, low held in registers across both passes ----
// thread t: eg = t&7 (e = 16*eg..16*eg+15), part = t>>3 (l = part + 32i)
// wave lane = (part&7)*8 + eg; part bits = lane bits 3..5, eg = lane bits 0..2
__global__ __launch_bounds__(256) void k_iter(
    const float* __restrict__ low, const float* __restrict__ Bm,
    const int* __restrict__ seq, float* __restrict__ acc0,
    float* __restrict__ acc1, float* __restrict__ out, int iter) {
    __shared__ float sW[3][SEQ];
    __shared__ float sPartB[3][4][128];
    __shared__ float sHigh[3][128];
    __shared__ float sDelta[3 * SEQ];

    const int t = threadIdx.x;
    const int lane = t & 63, w = t >> 6;
    const int eg = t & 7, part = t >> 3;
    const int b = blockIdx.x;
    const int n = seq[b];
    const float* lowb = low + (size_t)b * (SEQ * DIN);
    const f32x4 zz = {0.f, 0.f, 0.f, 0.f};

    // register-resident low slice: 7 l-values x 16 e-values
    f32x4 lw[7][4];
#pragma unroll
    for (int i = 0; i < 7; ++i) {
        int l = part + 32 * i;
        if (l < SEQ) {
#pragma unroll
            for (int c = 0; c < 4; ++c)
                lw[i][c] = *(const f32x4*)&lowb[l * DIN + eg * 16 + 4 * c];
        } else {
#pragma unroll
            for (int c = 0; c < 4; ++c) lw[i][c] = zz;
        }
    }

    // ---- Pass A: masked softmax (wave k handles row k) ----
    if (w < 3) {
        const int k = w;
        float m = -INFINITY;
        for (int l = lane; l < SEQ; l += 64) {
            float v = Bm[k * SEQ + l];
            if (iter >= 1) v += acc0[k * SEQ + l];
            if (iter >= 2) v += acc1[k * SEQ + l];
            if (l < n) m = fmaxf(m, v);
        }
        for (int off = 32; off; off >>= 1) m = fmaxf(m, __shfl_xor(m, off, 64));
        float s = 0.f;
        for (int l = lane; l < SEQ; l += 64) {
            float v = Bm[k * SEQ + l];
            if (iter >= 1) v += acc0[k * SEQ + l];
            if (iter >= 2) v += acc1[k * SEQ + l];
            float p = (l < n) ? expf(v - m) : 0.f;
            sW[k][l] = p;
            s += p;
        }
        for (int off = 32; off; off >>= 1) s += __shfl_xor(s, off, 64);
        float rs = 1.f / s;
        for (int l = lane; l < SEQ; l += 64) sW[k][l] *= rs;
    }
    __syncthreads();

    // ---- Pass B: high_pre[k][e] = sum_l W[k][l] * low[l][e] ----
#pragma unroll
    for (int k = 0; k < 3; ++k) {
        f32x4 h0 = zz, h1 = zz, h2 = zz, h3 = zz;
#pragma unroll
        for (int i = 0; i < 7; ++i) {
            int l = part + 32 * i;
            float wv = (l < SEQ) ? sW[k][l] : 0.f;
            h0 += wv * lw[i][0]; h1 += wv * lw[i][1];
            h2 += wv * lw[i][2]; h3 += wv * lw[i][3];
        }
        // reduce over the wave's 8 parts (lane bits 3..5)
#pragma unroll
        for (int off = 8; off <= 32; off <<= 1) {
#pragma unroll
            for (int c = 0; c < 4; ++c) {
                h0[c] += __shfl_xor(h0[c], off, 64);
                h1[c] += __shfl_xor(h1[c], off, 64);
                h2[c] += __shfl_xor(h2[c], off, 64);
                h3[c] += __shfl_xor(h3[c], off, 64);
            }
        }
        if (lane < 8) {   // one lane per eg holds the wave sum
            *(f32x4*)&sPartB[k][w][eg * 16 + 0]  = h0;
            *(f32x4*)&sPartB[k][w][eg * 16 + 4]  = h1;
            *(f32x4*)&sPartB[k][w][eg * 16 + 8]  = h2;
            *(f32x4*)&sPartB[k][w][eg * 16 + 12] = h3;
        }
    }
    __syncthreads();

    // ---- cross-wave reduce + squash (over k, per e) ----
    if (t < 128) {
        const int e = t;
        float g0 = sPartB[0][0][e] + sPartB[0][1][e] + sPartB[0][2][e] + sPartB[0][3][e];
        float g1 = sPartB[1][0][e] + sPartB[1][1][e] + sPartB[1][2][e] + sPartB[1][3][e];
        float g2 = sPartB[2][0][e] + sPartB[2][1][e] + sPartB[2][2][e] + sPartB[2][3][e];
        float sq = g0 * g0 + g1 * g1 + g2 * g2;
        float scale = sq / (1.f + sq) / sqrtf(sq + 1e-9f);
        g0 *= scale; g1 *= scale; g2 *= scale;
        if (iter == 2) {
            out[((size_t)b * 3 + 0) * DOUT + e] = g0;
            out[((size_t)b * 3 + 1) * DOUT + e] = g1;
            out[((size_t)b * 3 + 2) * DOUT + e] = g2;
        } else {
            sHigh[0][e] = g0; sHigh[1][e] = g1; sHigh[2][e] = g2;
        }
    }
    if (iter == 2) return;
    __syncthreads();

    // ---- Pass C: delta[k][l] = sum_e high[k][e] * low[l][e] ----
#pragma unroll
    for (int k = 0; k < 3; ++k) {
        f32x4 hg0 = *(const f32x4*)&sHigh[k][eg * 16 + 0];
        f32x4 hg1 = *(const f32x4*)&sHigh[k][eg * 16 + 4];
        f32x4 hg2 = *(const f32x4*)&sHigh[k][eg * 16 + 8];
        f32x4 hg3 = *(const f32x4*)&sHigh[k][eg * 16 + 12];
#pragma unroll
        for (int i = 0; i < 7; ++i) {
            f32x4 p = hg0 * lw[i][0] + hg1 * lw[i][1] + hg2 * lw[i][2] + hg3 * lw[i][3];
            float c = p[0] + p[1] + p[2] + p[3];
            c += __shfl_xor(c, 1, 64);   // reduce over eg (lane bits 0..2)
            c += __shfl_xor(c, 2, 64);
            c += __shfl_xor(c, 4, 64);
            int l = part + 32 * i;
            if (eg == 0 && l < SEQ) sDelta[k * SEQ + l] = c;
        }
    }
    __syncthreads();
    float* accN = (iter == 0) ? acc0 : acc1;
    for (int idx = t; idx < 3 * SEQ; idx += 256) atomicAdd(&accN[idx], sDelta[idx]);
}

extern "C" void kernel_launch(void* const* d_in, const int* in_sizes, int n_in,
                              void* d_out, int out_size, void* d_ws, size_t ws_size,
                              hipStream_t stream) {
    const float* low_capsule = (const float*)d_in[0];   // [1024][200][128]
    const float* B_matrix    = (const float*)d_in[1];   // [1][3][200]
    const float* S_matrix    = (const float*)d_in[2];   // [128][128]
    const int*   seq_len     = (const int*)d_in[3];     // [1024]
    float* out = (float*)d_out;                         // [1024][3][128]

    float* low_new = (float*)d_ws;                            // 26,214,400 floats
    short* Sp      = (short*)(low_new + (size_t)BATCH * SEQ * DOUT);  // 32768 shorts
    float* acc     = (float*)(Sp + 2 * 16384);                // acc0[600], acc1[600]

    hipMemsetAsync(acc, 0, 2 * 600 * sizeof(float), stream);

    k_presplit<<<64, 256, 0, stream>>>(S_matrix, Sp);
    k_gemm<<<(BATCH * SEQ) / 64, 256, 0, stream>>>(low_capsule, Sp, low_new);

    k_iter<<<BATCH, 256, 0, stream>>>(low_new, B_matrix, seq_len, acc, acc + 600, out, 0);
    k_iter<<<BATCH, 256, 0, stream>>>(low_new, B_matrix, seq_len, acc, acc + 600, out, 1);
    k_iter<<<BATCH, 256, 0, stream>>>(low_new, B_matrix, seq_len, acc, acc + 600, out, 2);
}